// Round 1
// baseline (2348.167 us; speedup 1.0000x reference)
//
#include <hip/hip_runtime.h>

// EdgeUpdate: out = silu(h@W3+b3) * (bonds_r@Wr+br),
//             h = silu(x@W1+b1) * sigmoid(x@W2+b2), x = [a_i | a_j | e_ij]
// Split x@W into per-atom precomputed parts (P table in d_ws) + per-edge part.

__device__ __forceinline__ float sigf(float x) {
    return __builtin_amdgcn_rcpf(1.0f + __expf(-x));
}
__device__ __forceinline__ float siluf(float x) {
    return x * sigf(x);
}

// ---------------------------------------------------------------------------
// Kernel 1: P[a][0:64]    = a@W1[0:64]   + b1
//           P[a][64:128]  = a@W1[64:128]
//           P[a][128:192] = a@W2[0:64]   + b2
//           P[a][192:256] = a@W2[64:128]
// ---------------------------------------------------------------------------
__global__ __launch_bounds__(256) void atom_proj_kernel(
    const float* __restrict__ atom_fea,
    const float* __restrict__ W1, const float* __restrict__ b1,
    const float* __restrict__ W2, const float* __restrict__ b2,
    float* __restrict__ P, int n_atoms)
{
    __shared__ float Wl[64 * 256];   // 64 KiB: Wl[k][cc]
    const int t = threadIdx.x;       // 0..255 = output channel cc

    for (int k = 0; k < 64; ++k) {
        float w;
        if (t < 64)        w = W1[k * 64 + t];
        else if (t < 128)  w = W1[(k + 64) * 64 + (t - 64)];
        else if (t < 192)  w = W2[k * 64 + (t - 128)];
        else               w = W2[(k + 64) * 64 + (t - 192)];
        Wl[k * 256 + t] = w;
    }
    float bias = 0.0f;
    if (t < 64)                    bias = b1[t];
    else if (t >= 128 && t < 192)  bias = b2[t - 128];
    __syncthreads();

    for (int a0 = blockIdx.x * 4; a0 < n_atoms; a0 += gridDim.x * 4) {
        if (a0 + 3 < n_atoms) {
            const float* af0 = atom_fea + (a0 + 0) * 64;
            const float* af1 = atom_fea + (a0 + 1) * 64;
            const float* af2 = atom_fea + (a0 + 2) * 64;
            const float* af3 = atom_fea + (a0 + 3) * 64;
            float acc0 = bias, acc1 = bias, acc2 = bias, acc3 = bias;
            #pragma unroll
            for (int k = 0; k < 64; ++k) {
                float w = Wl[k * 256 + t];   // conflict-free (2-way = free)
                acc0 = fmaf(af0[k], w, acc0);  // af*: wave-uniform -> s_load
                acc1 = fmaf(af1[k], w, acc1);
                acc2 = fmaf(af2[k], w, acc2);
                acc3 = fmaf(af3[k], w, acc3);
            }
            P[(a0 + 0) * 256 + t] = acc0;
            P[(a0 + 1) * 256 + t] = acc1;
            P[(a0 + 2) * 256 + t] = acc2;
            P[(a0 + 3) * 256 + t] = acc3;
        } else {
            for (int u = 0; u < 4; ++u) {
                int a = a0 + u;
                if (a >= n_atoms) break;
                const float* af = atom_fea + a * 64;
                float acc = bias;
                #pragma unroll
                for (int k = 0; k < 64; ++k)
                    acc = fmaf(af[k], Wl[k * 256 + t], acc);
                P[a * 256 + t] = acc;
            }
        }
    }
}

// ---------------------------------------------------------------------------
// Kernel 2: per-edge. One lane = one edge; wave = 64 edges.
// LDS: per-wave 64x68-float padded buffer (edge feats, then h, then out).
// ---------------------------------------------------------------------------
__global__ __launch_bounds__(256) void edge_kernel(
    const float* __restrict__ P,
    const float* __restrict__ edge_ij,
    const int*   __restrict__ nbr,
    const float* __restrict__ bonds_r,
    const float* __restrict__ W1c,   // W1 rows 128..191 (64x64)
    const float* __restrict__ W2c,   // W2 rows 128..191
    const float* __restrict__ W3,    // 64x64
    const float* __restrict__ b3,
    const float* __restrict__ Wr,    // 16x64
    const float* __restrict__ br,
    float* __restrict__ out,
    int n_edges)
{
    __shared__ float xbuf[4 * 64 * 68];          // 69,632 B -> 2 blocks/CU
    const int t    = threadIdx.x;
    const int wave = t >> 6;
    const int lane = t & 63;
    const int base = blockIdx.x * 256 + wave * 64;   // first edge of this wave
    float* xw   = xbuf + wave * (64 * 68);
    float* xrow = xw + lane * 68;

    const int nv = min(64, n_edges - base);      // valid edges in this wave

    // ---- stage edge_ij block coalesced into padded LDS rows ----
    if (nv > 0) {
        const float4* src = (const float4*)(edge_ij + base * 64);
        #pragma unroll
        for (int q = 0; q < 16; ++q) {
            int idx4 = q * 64 + lane;
            if (idx4 * 4 < nv * 64) {
                float4 v = src[idx4];
                int m = idx4 * 4;
                int er = m >> 6, kk = m & 63;
                *(float4*)&xw[er * 68 + kk] = v;
            }
        }
    }
    __syncthreads();

    const bool active = (lane < nv);
    const int e = base + lane;
    int ia = 0, ja = 0;
    if (active) { ia = nbr[e * 2]; ja = nbr[e * 2 + 1]; }
    const float* Pi = P + ia * 256;
    const float* Pj = P + ja * 256;

    // ---- init accumulators from gathered atom projections ----
    float2 a1[32], a2[32];
    #pragma unroll
    for (int c4 = 0; c4 < 16; ++c4) {
        float4 pa = ((const float4*)(Pi      ))[c4];
        float4 pb = ((const float4*)(Pj + 64 ))[c4];
        float4 qa = ((const float4*)(Pi + 128))[c4];
        float4 qb = ((const float4*)(Pj + 192))[c4];
        a1[2*c4+0] = make_float2(pa.x + pb.x, pa.y + pb.y);
        a1[2*c4+1] = make_float2(pa.z + pb.z, pa.w + pb.w);
        a2[2*c4+0] = make_float2(qa.x + qb.x, qa.y + qb.y);
        a2[2*c4+1] = make_float2(qa.z + qb.z, qa.w + qb.w);
    }

    // ---- main K loop: a1 += x @ W1c, a2 += x @ W2c ----
    #pragma unroll 4
    for (int k = 0; k < 64; ++k) {
        float xk = xrow[k];
        const float2* w1 = (const float2*)(W1c + k * 64);  // uniform -> s_load
        const float2* w2 = (const float2*)(W2c + k * 64);
        #pragma unroll
        for (int c2 = 0; c2 < 32; ++c2) {
            float2 w = w1[c2];
            a1[c2].x = fmaf(xk, w.x, a1[c2].x);
            a1[c2].y = fmaf(xk, w.y, a1[c2].y);
        }
        #pragma unroll
        for (int c2 = 0; c2 < 32; ++c2) {
            float2 w = w2[c2];
            a2[c2].x = fmaf(xk, w.x, a2[c2].x);
            a2[c2].y = fmaf(xk, w.y, a2[c2].y);
        }
    }

    // ---- h = silu(a1) * sigmoid(a2) -> own LDS row (runtime-k reads later) --
    #pragma unroll
    for (int c2 = 0; c2 < 32; ++c2) {
        float h0 = siluf(a1[c2].x) * sigf(a2[c2].x);
        float h1 = siluf(a1[c2].y) * sigf(a2[c2].y);
        *(float2*)&xrow[2 * c2] = make_float2(h0, h1);
    }

    // ---- a3 = b3 + h @ W3 ; g = br + bonds_r @ Wr ----
    float2 a3[32], g[32];
    #pragma unroll
    for (int c2 = 0; c2 < 32; ++c2) {
        a3[c2] = ((const float2*)b3)[c2];
        g[c2]  = ((const float2*)br)[c2];
    }
    #pragma unroll 4
    for (int k = 0; k < 64; ++k) {
        float hk = xrow[k];
        const float2* w3 = (const float2*)(W3 + k * 64);
        #pragma unroll
        for (int c2 = 0; c2 < 32; ++c2) {
            float2 w = w3[c2];
            a3[c2].x = fmaf(hk, w.x, a3[c2].x);
            a3[c2].y = fmaf(hk, w.y, a3[c2].y);
        }
    }
    {
        float4 rb[4];
        #pragma unroll
        for (int r = 0; r < 4; ++r)
            rb[r] = active ? ((const float4*)(bonds_r + e * 16))[r]
                           : make_float4(0.f, 0.f, 0.f, 0.f);
        #pragma unroll
        for (int r = 0; r < 4; ++r) {
            float bk[4] = { rb[r].x, rb[r].y, rb[r].z, rb[r].w };
            #pragma unroll
            for (int d = 0; d < 4; ++d) {
                const float2* wr = (const float2*)(Wr + (4 * r + d) * 64);
                #pragma unroll
                for (int c2 = 0; c2 < 32; ++c2) {
                    float2 w = wr[c2];
                    g[c2].x = fmaf(bk[d], w.x, g[c2].x);
                    g[c2].y = fmaf(bk[d], w.y, g[c2].y);
                }
            }
        }
    }

    // ---- out = silu(a3) * g -> LDS -> coalesced store ----
    #pragma unroll
    for (int c2 = 0; c2 < 32; ++c2) {
        float o0 = siluf(a3[c2].x) * g[c2].x;
        float o1 = siluf(a3[c2].y) * g[c2].y;
        *(float2*)&xrow[2 * c2] = make_float2(o0, o1);
    }
    __syncthreads();
    if (nv > 0) {
        float4* dst = (float4*)(out + base * 64);
        #pragma unroll
        for (int q = 0; q < 16; ++q) {
            int idx4 = q * 64 + lane;
            if (idx4 * 4 < nv * 64) {
                int m = idx4 * 4;
                int er = m >> 6, kk = m & 63;
                dst[idx4] = *(float4*)&xw[er * 68 + kk];
            }
        }
    }
}

// ---------------------------------------------------------------------------
extern "C" void kernel_launch(void* const* d_in, const int* in_sizes, int n_in,
                              void* d_out, int out_size, void* d_ws, size_t ws_size,
                              hipStream_t stream) {
    const float* atom_fea = (const float*)d_in[0];
    const float* edge_ij  = (const float*)d_in[1];
    const int*   nbr      = (const int*)  d_in[2];
    const float* bonds_r  = (const float*)d_in[3];
    const float* W1 = (const float*)d_in[4];
    const float* b1 = (const float*)d_in[5];
    const float* W2 = (const float*)d_in[6];
    const float* b2 = (const float*)d_in[7];
    const float* Wr = (const float*)d_in[8];
    const float* br = (const float*)d_in[9];
    const float* W3 = (const float*)d_in[10];
    const float* b3 = (const float*)d_in[11];
    float* out = (float*)d_out;
    float* P   = (float*)d_ws;               // 50000 * 256 floats = 51.2 MB

    const int n_atoms = in_sizes[0] / 64;
    const int n_edges = in_sizes[2] / 2;

    hipLaunchKernelGGL(atom_proj_kernel, dim3(512), dim3(256), 0, stream,
                       atom_fea, W1, b1, W2, b2, P, n_atoms);

    const int nblk = (n_edges + 255) / 256;
    hipLaunchKernelGGL(edge_kernel, dim3(nblk), dim3(256), 0, stream,
                       P, edge_ij, nbr, bonds_r,
                       W1 + 128 * 64, W2 + 128 * 64, W3, b3, Wr, br,
                       out, n_edges);
}

// Round 3
// 454.474 us; speedup vs baseline: 5.1668x; 5.1668x over previous
//
#include <hip/hip_runtime.h>
#include <hip/hip_bf16.h>

typedef float f32x4 __attribute__((ext_vector_type(4)));
typedef short s16x8 __attribute__((ext_vector_type(8)));

__device__ __forceinline__ unsigned short f2bf(float f) {
    union { __hip_bfloat16 b; unsigned short u; } v;
    v.b = __float2bfloat16(f);
    return v.u;
}
__device__ __forceinline__ float sigf(float x)  { return 1.0f / (1.0f + __expf(-x)); }
__device__ __forceinline__ float siluf(float x) { return x * sigf(x); }

__device__ __forceinline__ s16x8 pack8(float4 a, float4 b) {
    s16x8 r;
    r[0]=(short)f2bf(a.x); r[1]=(short)f2bf(a.y); r[2]=(short)f2bf(a.z); r[3]=(short)f2bf(a.w);
    r[4]=(short)f2bf(b.x); r[5]=(short)f2bf(b.y); r[6]=(short)f2bf(b.z); r[7]=(short)f2bf(b.w);
    return r;
}

// ---------------------------------------------------------------------------
// Kernel 1: per-atom projections. Natural channel order, sections arranged so
// the i-role gather ([sect0|sect2], bytes 0..511) and j-role gather
// ([sect1|sect3], bytes 512..1023) are each contiguous:
//   off 0:   sect0 = a@W1[0:64]  + b1
//   off 64:  sect2 = a@W2[0:64]  + b2
//   off 128: sect1 = a@W1[64:128]
//   off 192: sect3 = a@W2[64:128]
// ---------------------------------------------------------------------------
__global__ __launch_bounds__(256) void atom_proj_kernel(
    const float* __restrict__ atom_fea,
    const float* __restrict__ W1, const float* __restrict__ b1,
    const float* __restrict__ W2, const float* __restrict__ b2,
    float* __restrict__ Pp, int n_atoms)
{
    __shared__ float Wl[64 * 256];
    const int t = threadIdx.x;

    for (int k = 0; k < 64; ++k) {
        float w;
        if (t < 64)        w = W1[k * 64 + t];             // s=0
        else if (t < 128)  w = W1[(k + 64) * 64 + (t - 64)];   // s=1
        else if (t < 192)  w = W2[k * 64 + (t - 128)];     // s=2
        else               w = W2[(k + 64) * 64 + (t - 192)];  // s=3
        Wl[k * 256 + t] = w;
    }
    float bias = 0.0f;
    if (t < 64)                    bias = b1[t];
    else if (t >= 128 && t < 192)  bias = b2[t - 128];
    __syncthreads();

    const int s = t >> 6;
    const int c = t & 63;
    const int off_s = (s == 0) ? 0 : (s == 1) ? 128 : (s == 2) ? 64 : 192;
    const int dst_off = off_s + c;

    for (int a0 = blockIdx.x * 4; a0 < n_atoms; a0 += gridDim.x * 4) {
        if (a0 + 3 < n_atoms) {
            const float* af0 = atom_fea + (size_t)(a0 + 0) * 64;
            const float* af1 = atom_fea + (size_t)(a0 + 1) * 64;
            const float* af2 = atom_fea + (size_t)(a0 + 2) * 64;
            const float* af3 = atom_fea + (size_t)(a0 + 3) * 64;
            float acc0 = bias, acc1 = bias, acc2 = bias, acc3 = bias;
            #pragma unroll
            for (int k = 0; k < 64; ++k) {
                float w = Wl[k * 256 + t];
                acc0 = fmaf(af0[k], w, acc0);
                acc1 = fmaf(af1[k], w, acc1);
                acc2 = fmaf(af2[k], w, acc2);
                acc3 = fmaf(af3[k], w, acc3);
            }
            Pp[(size_t)(a0 + 0) * 256 + dst_off] = acc0;
            Pp[(size_t)(a0 + 1) * 256 + dst_off] = acc1;
            Pp[(size_t)(a0 + 2) * 256 + dst_off] = acc2;
            Pp[(size_t)(a0 + 3) * 256 + dst_off] = acc3;
        } else {
            for (int u = 0; u < 4; ++u) {
                int a = a0 + u;
                if (a >= n_atoms) break;
                const float* af = atom_fea + (size_t)a * 64;
                float acc = bias;
                #pragma unroll
                for (int k = 0; k < 64; ++k)
                    acc = fmaf(af[k], Wl[k * 256 + t], acc);
                Pp[(size_t)a * 256 + dst_off] = acc;
            }
        }
    }
}

// ---------------------------------------------------------------------------
// Kernel 2: MFMA edge kernel, wave = 16 edges x 64 channels, persistent.
// Split-half k-mapping: elem j<4 -> k=(l>>4)*4+j ; j>=4 -> k=16+(l>>4)*4+(j-4).
// Layer 1 swapped (W^T as A, x^T as B) so h is lane-local for layer 2's A.
// ---------------------------------------------------------------------------
#define NCH 28

__global__ __launch_bounds__(256, 2) void edge_kernel(
    const float* __restrict__ Pp,
    const float* __restrict__ edge_ij,
    const int*   __restrict__ nbr,
    const float* __restrict__ bonds_r,
    const float* __restrict__ W1, const float* __restrict__ W2,
    const float* __restrict__ W3, const float* __restrict__ b3,
    const float* __restrict__ Wr, const float* __restrict__ br,
    float* __restrict__ out, int n_edges)
{
    __shared__ unsigned short lds[NCH * 512];

    const int t    = threadIdx.x;
    const int wave = t >> 6;
    const int lane = t & 63;
    const int q    = lane >> 4;
    const int n    = lane & 15;

    // ---- stage weight fragments (B-layout; identical form serves as A=W^T):
    //      chunk element (l, j) = W[k = kh*32 + split(l>>4, j)][c = nb*16 + (l&15)]
    for (int ch = 0; ch < NCH; ++ch) {
        int idx = t * 2;
        #pragma unroll
        for (int e2 = 0; e2 < 2; ++e2, ++idx) {
            int l  = idx >> 3;
            int j  = idx & 7;
            int lq = l >> 4, ln = l & 15;
            int kk = (j < 4) ? (lq * 4 + j) : (16 + lq * 4 + (j - 4));
            float val;
            if (ch < 8) {
                int kh = ch >> 2, nb = ch & 3;
                val = W1[(size_t)(128 + kh * 32 + kk) * 64 + nb * 16 + ln];
            } else if (ch < 16) {
                int c2 = ch - 8; int kh = c2 >> 2, nb = c2 & 3;
                val = W2[(size_t)(128 + kh * 32 + kk) * 64 + nb * 16 + ln];
            } else if (ch < 24) {
                int c2 = ch - 16; int kh = c2 >> 2, nb = c2 & 3;
                val = W3[(size_t)(kh * 32 + kk) * 64 + nb * 16 + ln];
            } else {
                int nb = ch - 24;
                val = (kk < 16) ? Wr[(size_t)kk * 64 + nb * 16 + ln] : 0.0f;
            }
            lds[ch * 512 + idx] = f2bf(val);
        }
    }
    __syncthreads();

    float b3v[4], brv[4];
    #pragma unroll
    for (int nb = 0; nb < 4; ++nb) { b3v[nb] = b3[nb * 16 + n]; brv[nb] = br[nb * 16 + n]; }

    const int tiles  = (n_edges + 15) >> 4;
    const int stride = gridDim.x * 4;
    int T = blockIdx.x * 4 + wave;
    if (T >= tiles) return;

    const int2* nb2 = (const int2*)nbr;
    int2 nbcur = nb2[min(T * 16 + n, n_edges - 1)];   // this lane's own edge

    while (true) {
        const int E0 = T * 16;
        const int e  = min(E0 + n, n_edges - 1);
        const int Tn = T + stride;
        int2 nbnext = nbcur;
        if (Tn < tiles) nbnext = nb2[min(Tn * 16 + n, n_edges - 1)];

        // ---- P gathers -> accumulator C-in (swapped layout: [ch][edge n]) ----
        const float* Pi = Pp + (size_t)nbcur.x * 256;   // [sect0 | sect2]
        const float* Pj = Pp + (size_t)nbcur.y * 256;   // [sect1 | sect3] at +128
        f32x4 acc1[4], acc2[4];
        #pragma unroll
        for (int nb = 0; nb < 4; ++nb) {
            f32x4 s0 = *(const f32x4*)(Pi +       nb * 16 + q * 4);
            f32x4 s1 = *(const f32x4*)(Pj + 128 + nb * 16 + q * 4);
            f32x4 s2 = *(const f32x4*)(Pi +  64 + nb * 16 + q * 4);
            f32x4 s3 = *(const f32x4*)(Pj + 192 + nb * 16 + q * 4);
            acc1[nb] = s0 + s1;
            acc2[nb] = s2 + s3;
        }

        // ---- x^T B-frags: x[edge n][k = kh*32 + split(q, j)] ----
        const float* xr = edge_ij + (size_t)e * 64;
        float4 x00 = *(const float4*)(xr +      q * 4);
        float4 x01 = *(const float4*)(xr + 16 + q * 4);
        float4 x10 = *(const float4*)(xr + 32 + q * 4);
        float4 x11 = *(const float4*)(xr + 48 + q * 4);
        s16x8 xf0 = pack8(x00, x01);
        s16x8 xf1 = pack8(x10, x11);

        // ---- bonds A-frag: k = q*4+j (j<4, covers K=16), zero upper half ----
        float4 bl = *(const float4*)(bonds_r + (size_t)e * 16 + q * 4);
        s16x8 bfrag = pack8(bl, make_float4(0.f, 0.f, 0.f, 0.f));

        // ---- layer 1 swapped: acc[nb] = W^T chunk (A) x x^T (B) + P sums ----
        #pragma unroll
        for (int kh = 0; kh < 2; ++kh) {
            s16x8 xf = kh ? xf1 : xf0;
            #pragma unroll
            for (int nb = 0; nb < 4; ++nb) {
                s16x8 w = *(const s16x8*)&lds[(kh * 4 + nb) * 512 + lane * 8];
                acc1[nb] = __builtin_amdgcn_mfma_f32_16x16x32_bf16(w, xf, acc1[nb], 0, 0, 0);
            }
            #pragma unroll
            for (int nb = 0; nb < 4; ++nb) {
                s16x8 w = *(const s16x8*)&lds[(8 + kh * 4 + nb) * 512 + lane * 8];
                acc2[nb] = __builtin_amdgcn_mfma_f32_16x16x32_bf16(w, xf, acc2[nb], 0, 0, 0);
            }
        }

        // ---- h lane-local: lane(q,n) holds h[ch=nb*16+q*4+j][edge n].
        //      Layer-2 A-frag kh: elems 0..3 = ch kh*32+q*4+j  (nb=2kh),
        //                         elems 4..7 = ch kh*32+16+q*4+j (nb=2kh+1) ----
        s16x8 hf0, hf1;
        #pragma unroll
        for (int j = 0; j < 4; ++j) {
            hf0[j]     = (short)f2bf(siluf(acc1[0][j]) * sigf(acc2[0][j]));
            hf0[4 + j] = (short)f2bf(siluf(acc1[1][j]) * sigf(acc2[1][j]));
            hf1[j]     = (short)f2bf(siluf(acc1[2][j]) * sigf(acc2[2][j]));
            hf1[4 + j] = (short)f2bf(siluf(acc1[3][j]) * sigf(acc2[3][j]));
        }

        // ---- layer 2 (h @ W3) and gate (bonds @ Wr), normal orientation ----
        f32x4 a3[4], g[4];
        #pragma unroll
        for (int nb = 0; nb < 4; ++nb) { a3[nb] = (f32x4){0,0,0,0}; g[nb] = (f32x4){0,0,0,0}; }
        #pragma unroll
        for (int nb = 0; nb < 4; ++nb) {
            s16x8 w3a = *(const s16x8*)&lds[(16 + nb) * 512 + lane * 8];
            a3[nb] = __builtin_amdgcn_mfma_f32_16x16x32_bf16(hf0, w3a, a3[nb], 0, 0, 0);
            s16x8 w3b = *(const s16x8*)&lds[(20 + nb) * 512 + lane * 8];
            a3[nb] = __builtin_amdgcn_mfma_f32_16x16x32_bf16(hf1, w3b, a3[nb], 0, 0, 0);
            s16x8 wr  = *(const s16x8*)&lds[(24 + nb) * 512 + lane * 8];
            g[nb]  = __builtin_amdgcn_mfma_f32_16x16x32_bf16(bfrag, wr, g[nb], 0, 0, 0);
        }

        // ---- out[edge q*4+j][oc nb*16+n] = silu(a3+b3)*(g+br) ----
        #pragma unroll
        for (int nb = 0; nb < 4; ++nb) {
            #pragma unroll
            for (int j = 0; j < 4; ++j) {
                int grow = E0 + q * 4 + j;
                if (grow < n_edges) {
                    out[(size_t)grow * 64 + nb * 16 + n] =
                        siluf(a3[nb][j] + b3v[nb]) * (g[nb][j] + brv[nb]);
                }
            }
        }

        if (Tn >= tiles) break;
        T = Tn;
        nbcur = nbnext;
    }
}

// ---------------------------------------------------------------------------
extern "C" void kernel_launch(void* const* d_in, const int* in_sizes, int n_in,
                              void* d_out, int out_size, void* d_ws, size_t ws_size,
                              hipStream_t stream) {
    const float* atom_fea = (const float*)d_in[0];
    const float* edge_ij  = (const float*)d_in[1];
    const int*   nbr      = (const int*)  d_in[2];
    const float* bonds_r  = (const float*)d_in[3];
    const float* W1 = (const float*)d_in[4];
    const float* b1 = (const float*)d_in[5];
    const float* W2 = (const float*)d_in[6];
    const float* b2 = (const float*)d_in[7];
    const float* Wr = (const float*)d_in[8];
    const float* br = (const float*)d_in[9];
    const float* W3 = (const float*)d_in[10];
    const float* b3 = (const float*)d_in[11];
    float* out = (float*)d_out;
    float* Pp  = (float*)d_ws;               // 50000 * 256 floats = 51.2 MB

    const int n_atoms = in_sizes[0] / 64;
    const int n_edges = in_sizes[2] / 2;

    hipLaunchKernelGGL(atom_proj_kernel, dim3(512), dim3(256), 0, stream,
                       atom_fea, W1, b1, W2, b2, Pp, n_atoms);

    hipLaunchKernelGGL(edge_kernel, dim3(1024), dim3(256), 0, stream,
                       Pp, edge_ij, nbr, bonds_r,
                       W1, W2, W3, b3, Wr, br, out, n_edges);
}